// Round 7
// baseline (32703.873 us; speedup 1.0000x reference)
//
#include <hip/hip_runtime.h>

// MultilayerGRU: B=64 S=512 I=128 H=1024 L=3 O=128, fp32.
//
// R16: byte-diet retile on R11/R15's proven 4-dispatch structure.
// Model: per-tick traffic ~146 MB (65 weights + 43 input-panel re-reads +
// 38 partial round-trip) at ~2.8 TB/s = the 51 us/tick wall (explains R15's
// exact null: its changes were byte-neutral). This round cuts bytes:
//  - 128-wide n tiles (512-thread blocks, 4x4 microtile): input panel
//    re-read 16x -> 8x (43 -> 21.5 MB).
//  - Phase A kw=512 (3-5 slots/elem instead of 5-8): partials 25 -> 12.5 MB.
//  - Phase B kw=256, 96 tasks (keeps B wall short).
// Structure, dispatch pattern, reduce style (float4 over b, fixed slot
// order, deterministic) unchanged from R15.

namespace {
constexpr int kB = 64, kS = 512, kI = 128, kH = 1024, kO = 128;
constexpr int kTicks = kS + 3;               // tau = 0..514
constexpr size_t kBSO = (size_t)kB * kS * kO;
constexpr int kTasksA = 218, kTasksB = 96;

// Workspace (device globals)
__device__ float g_wxt0[3 * 128 * 1024];     // Wx0^T  [gate][k=I][n=H]
__device__ float g_wht0[3 * 1024 * 1024];    // Wh0^T  [gate][k][n]
__device__ float g_wxtr[6 * 1024 * 1024];    // Wxr^T  [(l-1)*3+gate][k][n]
__device__ float g_whtr[6 * 1024 * 1024];    // Whr^T
__device__ float g_woutT[1024 * 128];        // Wout^T [k=H][o=O]
__device__ float g_xT[512 * 128 * 64];       // x^T    [t][i][b]
__device__ float g_hbuf[2 * 3 * 1024 * 64];  // h^T    [parity][l][n][b]
__device__ float g_zT[3 * 1024 * 64];        // sigma(z) [l][n][b]
__device__ float g_rhT[3 * 1024 * 64];       // (r*h)^T[l][n][b]
__device__ float g_gxT[3 * 1024 * 64];       // g x-part + bias
__device__ float g_partA[kTasksA * 8192];    // [slot][cl*64+b], cl<128
__device__ float g_partB[kTasksB * 8192];
}  // namespace

// ---------------- setup kernels ----------------

__global__ void zero_hbuf() {
  g_hbuf[blockIdx.x * 256 + threadIdx.x] = 0.f;
}

// out[c][r] = in[r][c], batched over blockIdx.z. sel picks destination.
__global__ __launch_bounds__(256) void transpose_k(
    const float* __restrict__ in, int sel, int R, int C) {
  float* out;
  switch (sel) {
    case 0: out = g_wxt0; break;
    case 1: out = g_wht0; break;
    case 2: out = g_wxtr; break;
    case 3: out = g_whtr; break;
    case 4: out = g_woutT; break;
    default: out = g_xT; break;
  }
  const size_t mat = (size_t)R * C;
  in += blockIdx.z * mat;
  out += blockIdx.z * mat;
  __shared__ float t[32][33];
  const int c0 = blockIdx.x * 32, r0 = blockIdx.y * 32;
  const int tx = threadIdx.x & 31, ty = threadIdx.x >> 5;
  for (int i = ty; i < 32; i += 8) {
    const int r = r0 + i, c = c0 + tx;
    if (r < R && c < C) t[i][tx] = in[(size_t)r * C + c];
  }
  __syncthreads();
  for (int i = ty; i < 32; i += 8) {
    const int c = c0 + i, r = r0 + tx;
    if (c < C && r < R) out[(size_t)c * R + r] = t[tx][i];
  }
}

// ---------------- async staging helper ----------------
__device__ __forceinline__ void load_lds16(const float* g, float* l) {
  __builtin_amdgcn_global_load_lds(
      (const __attribute__((address_space(1))) void*)g,
      (__attribute__((address_space(3))) void*)l, 16, 0, 0);
}

// ---------------- main GEMM (split-K tasks, 128n x 64b, 512 thr) ----------
// Phase A slot map (218):
//  [  0, 48) l0 zr : gate*24 + ng*3 + ks   (ks0: x K=128; ks1,2: h 512-chunks)
//  [ 48,176) l1/l2 zr: 48+(l-1)*64+gate*32+ng*4+ks (ks0,1: x=h_{l-1} 512; ks2,3: h 512)
//  [176,184) gx l0 : 176+ng  (K=128)
//  [184,216) gx l1/l2: 184+(l-1)*16+ng*2+ks (512-chunks)
//  [216,218) y     : 216+ks  (512-chunks of h_l2, n-width 128 = full O)
// Phase B slot map (96): l*32 + ng*4 + ks (256-chunks of rhT).
__global__ __launch_bounds__(512) void gemm_tasks(int phase, int tau) {
  const int id = blockIdx.x;
  const int par = tau & 1;
  const float* hb = g_hbuf + par * 196608;  // [l][n][b]

  int t_l = 0, nk = 512, ldw = 1024;
  const float* inp = nullptr; const float* w = nullptr;

  if (phase == 0) {
    if (id < 48) {  // l0 zr
      const int gate = id / 24, q = id % 24, ng = q / 3, ks = q % 3;
      t_l = tau;
      if (ks == 0) {
        inp = g_xT + (size_t)t_l * 8192; nk = 128;
        w = g_wxt0 + (size_t)gate * 131072 + ng * 128;
      } else {
        const int k0 = (ks - 1) * 512;
        inp = hb + k0 * 64;
        w = g_wht0 + (size_t)gate * 1048576 + (size_t)k0 * 1024 + ng * 128;
      }
    } else if (id < 176) {  // l1/l2 zr
      const int q = id - 48, l = 1 + (q >> 6);
      const int q2 = q & 63, gate = q2 >> 5, q3 = q2 & 31, ng = q3 >> 2, ks = q3 & 3;
      t_l = tau - l;
      if (ks < 2) {
        const int k0 = ks * 512;
        inp = hb + (l - 1) * 65536 + k0 * 64;
        w = g_wxtr + (size_t)((l - 1) * 3 + gate) * 1048576 + (size_t)k0 * 1024 + ng * 128;
      } else {
        const int k0 = (ks - 2) * 512;
        inp = hb + l * 65536 + k0 * 64;
        w = g_whtr + (size_t)((l - 1) * 3 + gate) * 1048576 + (size_t)k0 * 1024 + ng * 128;
      }
    } else if (id < 184) {  // gx l0 (K=128)
      const int ng = id - 176;
      t_l = tau;
      inp = g_xT + (size_t)t_l * 8192; nk = 128;
      w = g_wxt0 + (size_t)2 * 131072 + ng * 128;
    } else if (id < 216) {  // gx l1/l2
      const int q = id - 184, l = 1 + (q >> 4);
      const int q2 = q & 15, ng = q2 >> 1, ks = q2 & 1;
      t_l = tau - l;
      const int k0 = ks * 512;
      inp = hb + (l - 1) * 65536 + k0 * 64;
      w = g_wxtr + (size_t)((l - 1) * 3 + 2) * 1048576 + (size_t)k0 * 1024 + ng * 128;
    } else {  // y (n-width 128 = full O)
      const int ks = id - 216;
      t_l = tau - 3;
      const int k0 = ks * 512;
      inp = hb + 2 * 65536 + k0 * 64;
      w = g_woutT + (size_t)k0 * 128; ldw = 128;
    }
  } else {  // phase B: g h-part over rhT, kw=256
    const int l = id >> 5, q = id & 31, ng = q >> 2, ks = q & 3;
    t_l = tau - l;
    const int k0 = ks * 256;
    inp = g_rhT + l * 65536 + k0 * 64; nk = 256;
    w = ((l == 0) ? g_wht0 + (size_t)2 * 1048576
                  : g_whtr + (size_t)((l - 1) * 3 + 2) * 1048576) +
        (size_t)k0 * 1024 + ng * 128;
  }
  if (t_l < 0 || t_l >= kS) return;  // inactive this tick

  __shared__ float sI[64 * 64];   // [k][b]   16 KB
  __shared__ float sW[64 * 128];  // [k][n]   32 KB
  const int tid = threadIdx.x;
  const int tn = (tid & 31) * 4, tb = (tid >> 5) * 4;
  float acc[4][4] = {};

  for (int c0 = 0; c0 < nk; c0 += 64) {
    // async global->LDS staging (dest linear in tid; per-lane global src)
#pragma unroll
    for (int u = 0; u < 2; ++u) {
      const int idx = tid + u * 512;
      load_lds16(inp + c0 * 64 + idx * 4, sI + idx * 4);
    }
#pragma unroll
    for (int u = 0; u < 4; ++u) {
      const int idx = tid + u * 512, k = idx >> 5, f = idx & 31;
      load_lds16(w + (size_t)(c0 + k) * ldw + f * 4, sW + idx * 4);
    }
    __syncthreads();  // drains vmcnt before barrier
#pragma unroll 8
    for (int k = 0; k < 64; ++k) {
      const float4 a = *(const float4*)(sI + k * 64 + tb);
      const float4 wv = *(const float4*)(sW + k * 128 + tn);
      acc[0][0] += wv.x * a.x; acc[0][1] += wv.x * a.y; acc[0][2] += wv.x * a.z; acc[0][3] += wv.x * a.w;
      acc[1][0] += wv.y * a.x; acc[1][1] += wv.y * a.y; acc[1][2] += wv.y * a.z; acc[1][3] += wv.y * a.w;
      acc[2][0] += wv.z * a.x; acc[2][1] += wv.z * a.y; acc[2][2] += wv.z * a.z; acc[2][3] += wv.z * a.w;
      acc[3][0] += wv.w * a.x; acc[3][1] += wv.w * a.y; acc[3][2] += wv.w * a.z; acc[3][3] += wv.w * a.w;
    }
    __syncthreads();
  }

  float* po = ((phase == 0) ? g_partA : g_partB) + (size_t)id * 8192;
#pragma unroll
  for (int i = 0; i < 4; ++i) {
    float4 v = {acc[i][0], acc[i][1], acc[i][2], acc[i][3]};
    *(float4*)(po + (tn + i) * 64 + tb) = v;
  }
}

// ---------------- reduce A: z=sigma, r=sigma, rh^T, gx^T, y ----------------
// columns: [0,3072) z | [3072,6144) r | [6144,9216) gx | [9216,9344) y
// 4 consecutive b per thread (float4); grid 584 x 256 = 9344*16 threads.
__global__ __launch_bounds__(256) void reduceA(
    int tau, const float* __restrict__ Bh0, const float* __restrict__ Bhr,
    const float* __restrict__ Bout, float* __restrict__ Out) {
  const int gid = blockIdx.x * 256 + threadIdx.x;
  const int b0 = (gid & 15) * 4, c = gid >> 4;
  const int par = tau & 1;
  if (c < 6144) {  // z or r gate
    const int gate = (c >= 3072) ? 1 : 0;
    const int cc = c - gate * 3072;
    const int l = cc >> 10, n = cc & 1023;
    const int t_l = tau - l;
    if (t_l < 0 || t_l >= kS) return;
    const int ng = n >> 7, cl = n & 127;
    int base, nks;
    if (l == 0) { base = gate * 24 + ng * 3;                  nks = 3; }
    else        { base = 48 + (l - 1) * 64 + gate * 32 + ng * 4; nks = 4; }
    const float bias = (l == 0) ? Bh0[gate * 1024 + n] : Bhr[(l - 1) * 3072 + gate * 1024 + n];
    float s0 = bias, s1 = bias, s2 = bias, s3 = bias;
    for (int j = 0; j < nks; ++j) {
      const float4 p = *(const float4*)&g_partA[(size_t)(base + j) * 8192 + cl * 64 + b0];
      s0 += p.x; s1 += p.y; s2 += p.z; s3 += p.w;
    }
    const float v0 = 1.f / (1.f + expf(-s0)), v1 = 1.f / (1.f + expf(-s1));
    const float v2 = 1.f / (1.f + expf(-s2)), v3 = 1.f / (1.f + expf(-s3));
    const int off = l * 65536 + n * 64 + b0;
    if (gate == 0) {
      *(float4*)&g_zT[off] = make_float4(v0, v1, v2, v3);
    } else {
      const float4 h = *(const float4*)&g_hbuf[par * 196608 + off];
      *(float4*)&g_rhT[off] = make_float4(v0 * h.x, v1 * h.y, v2 * h.z, v3 * h.w);
    }
  } else if (c < 9216) {  // g x-part + bias
    const int cc = c - 6144, l = cc >> 10, n = cc & 1023;
    const int t_l = tau - l;
    if (t_l < 0 || t_l >= kS) return;
    const int ng = n >> 7, cl = n & 127;
    int base, nks;
    if (l == 0) { base = 176 + ng;                 nks = 1; }
    else        { base = 184 + (l - 1) * 16 + ng * 2; nks = 2; }
    const float bias = (l == 0) ? Bh0[2048 + n] : Bhr[(l - 1) * 3072 + 2048 + n];
    float s0 = bias, s1 = bias, s2 = bias, s3 = bias;
    for (int j = 0; j < nks; ++j) {
      const float4 p = *(const float4*)&g_partA[(size_t)(base + j) * 8192 + cl * 64 + b0];
      s0 += p.x; s1 += p.y; s2 += p.z; s3 += p.w;
    }
    *(float4*)&g_gxT[l * 65536 + n * 64 + b0] = make_float4(s0, s1, s2, s3);
  } else {  // y (tile is 128 wide: cl = o)
    const int o = c - 9216, ty = tau - 3;
    if (ty < 0 || ty >= kS) return;
    const float bias = Bout[o];
    float s0 = bias, s1 = bias, s2 = bias, s3 = bias;
    for (int j = 0; j < 2; ++j) {
      const float4 p = *(const float4*)&g_partA[(size_t)(216 + j) * 8192 + o * 64 + b0];
      s0 += p.x; s1 += p.y; s2 += p.z; s3 += p.w;
    }
    Out[((size_t)(b0 + 0) * kS + ty) * kO + o] = s0;
    Out[((size_t)(b0 + 1) * kS + ty) * kO + o] = s1;
    Out[((size_t)(b0 + 2) * kS + ty) * kO + o] = s2;
    Out[((size_t)(b0 + 3) * kS + ty) * kO + o] = s3;
  }
}

// ---------------- reduce B: g=tanh(gx+gh), h' = z*h + (1-z)*g ----------------
// 4 consecutive b per thread; grid 192 x 256 = 3072*16 threads.
__global__ __launch_bounds__(256) void reduceB(
    int tau, float* __restrict__ Out) {
  const int gid = blockIdx.x * 256 + threadIdx.x;
  const int b0 = (gid & 15) * 4, c = gid >> 4;
  const int l = c >> 10, n = c & 1023;
  const int t_l = tau - l;
  if (t_l < 0 || t_l >= kS) return;
  const int par = tau & 1;
  const int ng = n >> 7, cl = n & 127;
  const int base = l * 32 + ng * 4;
  const int off = l * 65536 + n * 64 + b0;
  float4 gs = *(const float4*)&g_gxT[off];
  for (int j = 0; j < 4; ++j) {
    const float4 p = *(const float4*)&g_partB[(size_t)(base + j) * 8192 + cl * 64 + b0];
    gs.x += p.x; gs.y += p.y; gs.z += p.z; gs.w += p.w;
  }
  const float g0 = tanhf(gs.x), g1 = tanhf(gs.y), g2 = tanhf(gs.z), g3 = tanhf(gs.w);
  const float4 z = *(const float4*)&g_zT[off];
  const float4 h = *(const float4*)&g_hbuf[par * 196608 + off];
  float4 hn;
  hn.x = z.x * h.x + (1.f - z.x) * g0;
  hn.y = z.y * h.y + (1.f - z.y) * g1;
  hn.z = z.z * h.z + (1.f - z.z) * g2;
  hn.w = z.w * h.w + (1.f - z.w) * g3;
  *(float4*)&g_hbuf[(1 - par) * 196608 + off] = hn;
  if (t_l == kS - 1) {
    Out[kBSO + ((size_t)(b0 + 0) * 3 + l) * 1024 + n] = hn.x;
    Out[kBSO + ((size_t)(b0 + 1) * 3 + l) * 1024 + n] = hn.y;
    Out[kBSO + ((size_t)(b0 + 2) * 3 + l) * 1024 + n] = hn.z;
    Out[kBSO + ((size_t)(b0 + 3) * 3 + l) * 1024 + n] = hn.w;
  }
}

// ---------------- host ----------------
extern "C" void kernel_launch(void* const* d_in, const int* in_sizes, int n_in,
                              void* d_out, int out_size, void* d_ws, size_t ws_size,
                              hipStream_t stream) {
  const float* X    = (const float*)d_in[0];
  const float* Wx0  = (const float*)d_in[1];
  const float* Wh0  = (const float*)d_in[2];
  const float* bh0  = (const float*)d_in[3];
  const float* Wxr  = (const float*)d_in[4];
  const float* Whr  = (const float*)d_in[5];
  const float* bhr  = (const float*)d_in[6];
  const float* Wout = (const float*)d_in[7];
  const float* bout = (const float*)d_in[8];
  (void)d_ws; (void)ws_size;

  if (n_in != 9 ||
      in_sizes[0] != 64 * 512 * 128 || in_sizes[1] != 3 * 1024 * 128 ||
      in_sizes[2] != 3 * 1024 * 1024 || in_sizes[3] != 3 * 1024 ||
      in_sizes[4] != 2 * 3 * 1024 * 1024 || in_sizes[5] != 2 * 3 * 1024 * 1024 ||
      in_sizes[6] != 2 * 3 * 1024 || in_sizes[7] != 128 * 1024 ||
      in_sizes[8] != 128 || out_size != 64 * 512 * 128 + 64 * 3 * 1024)
    return;  // diagnostic: out stays 0

  float* out = (float*)d_out;

  hipLaunchKernelGGL(zero_hbuf, dim3(1536), dim3(256), 0, stream);
  hipLaunchKernelGGL(transpose_k, dim3(4, 32, 3),   dim3(256), 0, stream, Wx0,  0, 1024, 128);
  hipLaunchKernelGGL(transpose_k, dim3(32, 32, 3),  dim3(256), 0, stream, Wh0,  1, 1024, 1024);
  hipLaunchKernelGGL(transpose_k, dim3(32, 32, 6),  dim3(256), 0, stream, Wxr,  2, 1024, 1024);
  hipLaunchKernelGGL(transpose_k, dim3(32, 32, 6),  dim3(256), 0, stream, Whr,  3, 1024, 1024);
  hipLaunchKernelGGL(transpose_k, dim3(32, 4, 1),   dim3(256), 0, stream, Wout, 4, 128, 1024);
  hipLaunchKernelGGL(transpose_k, dim3(2048, 2, 1), dim3(256), 0, stream, X,    5, 64, 65536);

  for (int tau = 0; tau < kTicks; ++tau) {
    hipLaunchKernelGGL(gemm_tasks, dim3(kTasksA), dim3(512), 0, stream, 0, tau);
    hipLaunchKernelGGL(reduceA, dim3(584), dim3(256), 0, stream,
                       tau, bh0, bhr, bout, out);
    if (tau < kTicks - 1) {
      hipLaunchKernelGGL(gemm_tasks, dim3(kTasksB), dim3(512), 0, stream, 1, tau);
      hipLaunchKernelGGL(reduceB, dim3(192), dim3(256), 0, stream, tau, out);
    }
  }
}

// Round 8
// 27284.933 us; speedup vs baseline: 1.1986x; 1.1986x over previous
//
#include <hip/hip_runtime.h>

// MultilayerGRU: B=64 S=512 I=128 H=1024 L=3 O=128, fp32.
//
// R17: byte-diet with correct geometry. R16's regression was task geometry
// (512-thr, 1 block/CU, 13.6us K-chains), not the byte cut. This round:
//  - gemmA: 128-wide n-tiles, 256 threads, kw=256, 8nx4b microtile.
//    K-chain 6.8us (= R11's), 412 tasks (~1.6/CU), LDS 48KB (3 blocks/CU).
//    Input-panel re-reads x16 -> x8: A staged bytes ~52 -> ~37 MB/tick.
//  - reduceA = r-only (grid 192). z/gx/y reductions folded into reduceB
//    (same per-output summation order).
//  - Phase B (gemmB 64-wide kw=128, 384 tasks) and its slots: R15-verbatim.
// Structure stays 4 dispatches/tick, kernel boundary = sync, no atomics.

namespace {
constexpr int kB = 64, kS = 512, kI = 128, kH = 1024, kO = 128;
constexpr int kTicks = kS + 3;               // tau = 0..514
constexpr size_t kBSO = (size_t)kB * kS * kO;
constexpr int kTasksA = 412, kTasksB = 384;

// Workspace (device globals)
__device__ float g_wxt0[3 * 128 * 1024];     // Wx0^T  [gate][k=I][n=H]
__device__ float g_wht0[3 * 1024 * 1024];    // Wh0^T  [gate][k][n]
__device__ float g_wxtr[6 * 1024 * 1024];    // Wxr^T  [(l-1)*3+gate][k][n]
__device__ float g_whtr[6 * 1024 * 1024];    // Whr^T
__device__ float g_woutT[1024 * 128];        // Wout^T [k=H][o=O]
__device__ float g_xT[512 * 128 * 64];       // x^T    [t][i][b]
__device__ float g_hbuf[2 * 3 * 1024 * 64];  // h^T    [parity][l][n][b]
__device__ float g_rhT[3 * 1024 * 64];       // (r*h)^T[l][n][b]
__device__ float g_partA[kTasksA * 8192];    // [slot][cl*64+b], cl<128
__device__ float g_partB[kTasksB * 4096];    // [slot][cl*64+b], cl<64
}  // namespace

// ---------------- setup kernels ----------------

__global__ void zero_hbuf() {
  g_hbuf[blockIdx.x * 256 + threadIdx.x] = 0.f;
}

// out[c][r] = in[r][c], batched over blockIdx.z. sel picks destination.
__global__ __launch_bounds__(256) void transpose_k(
    const float* __restrict__ in, int sel, int R, int C) {
  float* out;
  switch (sel) {
    case 0: out = g_wxt0; break;
    case 1: out = g_wht0; break;
    case 2: out = g_wxtr; break;
    case 3: out = g_whtr; break;
    case 4: out = g_woutT; break;
    default: out = g_xT; break;
  }
  const size_t mat = (size_t)R * C;
  in += blockIdx.z * mat;
  out += blockIdx.z * mat;
  __shared__ float t[32][33];
  const int c0 = blockIdx.x * 32, r0 = blockIdx.y * 32;
  const int tx = threadIdx.x & 31, ty = threadIdx.x >> 5;
  for (int i = ty; i < 32; i += 8) {
    const int r = r0 + i, c = c0 + tx;
    if (r < R && c < C) t[i][tx] = in[(size_t)r * C + c];
  }
  __syncthreads();
  for (int i = ty; i < 32; i += 8) {
    const int c = c0 + i, r = r0 + tx;
    if (c < C && r < R) out[(size_t)c * R + r] = t[tx][i];
  }
}

// ---------------- async staging helper ----------------
__device__ __forceinline__ void load_lds16(const float* g, float* l) {
  __builtin_amdgcn_global_load_lds(
      (const __attribute__((address_space(1))) void*)g,
      (__attribute__((address_space(3))) void*)l, 16, 0, 0);
}

// ---------------- phase A GEMM: 128n x 64b tiles, kw=256 ----------------
// Slot map (412):
//  [  0, 80) l0 zr : gate*40 + ng*5 + ks  (ks0: x K=128; ks1-4: h 256-chunks)
//  [ 80,336) l1/l2 zr: 80+(l-1)*128+gate*64+ng*8+ks (ks0-3: x=h_{l-1}; ks4-7: h)
//  [336,344) gx l0 : 336+ng (K=128)
//  [344,408) gx l1/l2: 344+(l-1)*32+ng*4+ks (256-chunks)
//  [408,412) y     : 408+ks (256-chunks of h_l2; n-width 128 = full O)
__global__ __launch_bounds__(256) void gemmA(int tau) {
  const int id = blockIdx.x;
  const int par = tau & 1;
  const float* hb = g_hbuf + par * 196608;  // [l][n][b]

  int t_l = 0, nk = 256, ldw = 1024;
  const float* inp = nullptr; const float* w = nullptr;

  if (id < 80) {  // l0 zr
    const int gate = id / 40, q = id % 40, ng = q / 5, ks = q % 5;
    t_l = tau;
    if (ks == 0) {
      inp = g_xT + (size_t)t_l * 8192; nk = 128;
      w = g_wxt0 + (size_t)gate * 131072 + ng * 128;
    } else {
      const int k0 = (ks - 1) * 256;
      inp = hb + k0 * 64;
      w = g_wht0 + (size_t)gate * 1048576 + (size_t)k0 * 1024 + ng * 128;
    }
  } else if (id < 336) {  // l1/l2 zr
    const int q = id - 80, l = 1 + (q >> 7);
    const int q2 = q & 127, gate = q2 >> 6, q3 = q2 & 63, ng = q3 >> 3, ks = q3 & 7;
    t_l = tau - l;
    const int k0 = (ks & 3) * 256;
    if (ks < 4) {
      inp = hb + (l - 1) * 65536 + k0 * 64;
      w = g_wxtr + (size_t)((l - 1) * 3 + gate) * 1048576 + (size_t)k0 * 1024 + ng * 128;
    } else {
      inp = hb + l * 65536 + k0 * 64;
      w = g_whtr + (size_t)((l - 1) * 3 + gate) * 1048576 + (size_t)k0 * 1024 + ng * 128;
    }
  } else if (id < 344) {  // gx l0 (K=128)
    const int ng = id - 336;
    t_l = tau;
    inp = g_xT + (size_t)t_l * 8192; nk = 128;
    w = g_wxt0 + (size_t)2 * 131072 + ng * 128;
  } else if (id < 408) {  // gx l1/l2
    const int q = id - 344, l = 1 + (q >> 5);
    const int q2 = q & 31, ng = q2 >> 2, ks = q2 & 3;
    t_l = tau - l;
    const int k0 = ks * 256;
    inp = hb + (l - 1) * 65536 + k0 * 64;
    w = g_wxtr + (size_t)((l - 1) * 3 + 2) * 1048576 + (size_t)k0 * 1024 + ng * 128;
  } else {  // y (n-width 128 = full O)
    const int ks = id - 408;
    t_l = tau - 3;
    const int k0 = ks * 256;
    inp = hb + 2 * 65536 + k0 * 64;
    w = g_woutT + (size_t)k0 * 128; ldw = 128;
  }
  if (t_l < 0 || t_l >= kS) return;  // inactive this tick

  __shared__ float sI[64 * 64];   // [k][b]  16 KB
  __shared__ float sW[64 * 128];  // [k][n]  32 KB
  const int tid = threadIdx.x;
  const int tn = (tid & 15) * 8, tb = (tid >> 4) * 4;
  float acc[8][4] = {};

  for (int c0 = 0; c0 < nk; c0 += 64) {
    // async global->LDS staging (dest linear in tid; per-lane global src)
#pragma unroll
    for (int u = 0; u < 4; ++u) {
      const int idx = tid + u * 256;
      load_lds16(inp + c0 * 64 + idx * 4, sI + idx * 4);
    }
#pragma unroll
    for (int u = 0; u < 8; ++u) {
      const int idx = tid + u * 256, k = idx >> 5, f = idx & 31;
      load_lds16(w + (size_t)(c0 + k) * ldw + f * 4, sW + idx * 4);
    }
    __syncthreads();  // drains vmcnt before barrier
#pragma unroll 4
    for (int k = 0; k < 64; ++k) {
      const float4 a = *(const float4*)(sI + k * 64 + tb);
      const float4 w0 = *(const float4*)(sW + k * 128 + tn);
      const float4 w1 = *(const float4*)(sW + k * 128 + tn + 4);
      acc[0][0] += w0.x * a.x; acc[0][1] += w0.x * a.y; acc[0][2] += w0.x * a.z; acc[0][3] += w0.x * a.w;
      acc[1][0] += w0.y * a.x; acc[1][1] += w0.y * a.y; acc[1][2] += w0.y * a.z; acc[1][3] += w0.y * a.w;
      acc[2][0] += w0.z * a.x; acc[2][1] += w0.z * a.y; acc[2][2] += w0.z * a.z; acc[2][3] += w0.z * a.w;
      acc[3][0] += w0.w * a.x; acc[3][1] += w0.w * a.y; acc[3][2] += w0.w * a.z; acc[3][3] += w0.w * a.w;
      acc[4][0] += w1.x * a.x; acc[4][1] += w1.x * a.y; acc[4][2] += w1.x * a.z; acc[4][3] += w1.x * a.w;
      acc[5][0] += w1.y * a.x; acc[5][1] += w1.y * a.y; acc[5][2] += w1.y * a.z; acc[5][3] += w1.y * a.w;
      acc[6][0] += w1.z * a.x; acc[6][1] += w1.z * a.y; acc[6][2] += w1.z * a.z; acc[6][3] += w1.z * a.w;
      acc[7][0] += w1.w * a.x; acc[7][1] += w1.w * a.y; acc[7][2] += w1.w * a.z; acc[7][3] += w1.w * a.w;
    }
    __syncthreads();
  }

  float* po = g_partA + (size_t)id * 8192;
#pragma unroll
  for (int i = 0; i < 8; ++i) {
    float4 v = {acc[i][0], acc[i][1], acc[i][2], acc[i][3]};
    *(float4*)(po + (tn + i) * 64 + tb) = v;
  }
}

// ---------------- phase B GEMM: 64n x 64b, kw=128 (R15-verbatim) ---------
// Slots (384): l*128 + tile*8 + ks (128-chunks of rhT).
__global__ __launch_bounds__(256, 2) void gemmB(int tau) {
  const int id = blockIdx.x;
  const int l = id >> 7;
  const int rem = id & 127, tile = rem >> 3, ks = rem & 7;
  const int t_l = tau - l;
  if (t_l < 0 || t_l >= kS) return;
  const int k0 = ks * 128;
  const float* inp = g_rhT + l * 65536 + k0 * 64;
  const float* w =
      ((l == 0) ? g_wht0 + (size_t)2 * 1048576
                : g_whtr + (size_t)((l - 1) * 3 + 2) * 1048576) +
      (size_t)k0 * 1024 + tile * 64;

  __shared__ float sI[64 * 64];
  __shared__ float sW[64 * 64];
  const int tid = threadIdx.x;
  const int tn = (tid & 15) * 4, tb = (tid >> 4) * 4;
  float acc[4][4] = {};

  for (int c0 = 0; c0 < 128; c0 += 64) {
#pragma unroll
    for (int u = 0; u < 4; ++u) {
      const int idx = tid + u * 256;
      load_lds16(inp + c0 * 64 + idx * 4, sI + idx * 4);
    }
#pragma unroll
    for (int u = 0; u < 4; ++u) {
      const int idx = tid + u * 256, k = idx >> 4, f = idx & 15;
      load_lds16(w + (size_t)(c0 + k) * 1024 + f * 4, sW + idx * 4);
    }
    __syncthreads();
#pragma unroll 8
    for (int k = 0; k < 64; ++k) {
      const float4 a = *(const float4*)(sI + k * 64 + tb);
      const float4 wv = *(const float4*)(sW + k * 64 + tn);
      acc[0][0] += wv.x * a.x; acc[0][1] += wv.x * a.y; acc[0][2] += wv.x * a.z; acc[0][3] += wv.x * a.w;
      acc[1][0] += wv.y * a.x; acc[1][1] += wv.y * a.y; acc[1][2] += wv.y * a.z; acc[1][3] += wv.y * a.w;
      acc[2][0] += wv.z * a.x; acc[2][1] += wv.z * a.y; acc[2][2] += wv.z * a.z; acc[2][3] += wv.z * a.w;
      acc[3][0] += wv.w * a.x; acc[3][1] += wv.w * a.y; acc[3][2] += wv.w * a.z; acc[3][3] += wv.w * a.w;
    }
    __syncthreads();
  }

  float* po = g_partB + (size_t)id * 4096;
#pragma unroll
  for (int i = 0; i < 4; ++i) {
    float4 v = {acc[i][0], acc[i][1], acc[i][2], acc[i][3]};
    *(float4*)(po + (tn + i) * 64 + tb) = v;
  }
}

// ---------------- reduce A: r = sigma(.), rhT only ----------------
// cols [0,3072); 4 consecutive b per thread; grid 192 x 256.
__global__ __launch_bounds__(256) void reduceA(
    int tau, const float* __restrict__ Bh0, const float* __restrict__ Bhr) {
  const int gid = blockIdx.x * 256 + threadIdx.x;
  const int b0 = (gid & 15) * 4, c = gid >> 4;
  const int par = tau & 1;
  const int l = c >> 10, n = c & 1023;
  const int t_l = tau - l;
  if (t_l < 0 || t_l >= kS) return;
  const int ng = n >> 7, cl = n & 127;
  int base, nks;
  if (l == 0) { base = 40 + ng * 5; nks = 5; }
  else        { base = 80 + (l - 1) * 128 + 64 + ng * 8; nks = 8; }
  const float bias = (l == 0) ? Bh0[1024 + n] : Bhr[(l - 1) * 3072 + 1024 + n];
  float s0 = bias, s1 = bias, s2 = bias, s3 = bias;
  for (int j = 0; j < nks; ++j) {
    const float4 p = *(const float4*)&g_partA[(size_t)(base + j) * 8192 + cl * 64 + b0];
    s0 += p.x; s1 += p.y; s2 += p.z; s3 += p.w;
  }
  const float v0 = 1.f / (1.f + expf(-s0)), v1 = 1.f / (1.f + expf(-s1));
  const float v2 = 1.f / (1.f + expf(-s2)), v3 = 1.f / (1.f + expf(-s3));
  const int off = l * 65536 + n * 64 + b0;
  const float4 h = *(const float4*)&g_hbuf[par * 196608 + off];
  *(float4*)&g_rhT[off] = make_float4(v0 * h.x, v1 * h.y, v2 * h.z, v3 * h.w);
}

// ---------------- reduce B: z, g=tanh(gx+gh), h-update, y ----------------
// cols [0,3072) gates | [3072,3200) y; grid 200 x 256.
__global__ __launch_bounds__(256) void reduceB(
    int tau, const float* __restrict__ Bh0, const float* __restrict__ Bhr,
    const float* __restrict__ Bout, float* __restrict__ Out) {
  const int gid = blockIdx.x * 256 + threadIdx.x;
  const int b0 = (gid & 15) * 4, c = gid >> 4;
  const int par = tau & 1;
  if (c < 3072) {
    const int l = c >> 10, n = c & 1023;
    const int t_l = tau - l;
    if (t_l < 0 || t_l >= kS) return;
    const int ng = n >> 7, cl = n & 127;
    // z gate from phase-A slots
    int zbase, znks;
    if (l == 0) { zbase = ng * 5; znks = 5; }
    else        { zbase = 80 + (l - 1) * 128 + ng * 8; znks = 8; }
    const float zb = (l == 0) ? Bh0[n] : Bhr[(l - 1) * 3072 + n];
    float z0 = zb, z1 = zb, z2 = zb, z3 = zb;
    for (int j = 0; j < znks; ++j) {
      const float4 p = *(const float4*)&g_partA[(size_t)(zbase + j) * 8192 + cl * 64 + b0];
      z0 += p.x; z1 += p.y; z2 += p.z; z3 += p.w;
    }
    z0 = 1.f / (1.f + expf(-z0)); z1 = 1.f / (1.f + expf(-z1));
    z2 = 1.f / (1.f + expf(-z2)); z3 = 1.f / (1.f + expf(-z3));
    // g pre-act: bias + gx slots (phase A) + gh slots (phase B)
    int gxbase, gxn;
    if (l == 0) { gxbase = 336 + ng; gxn = 1; }
    else        { gxbase = 344 + (l - 1) * 32 + ng * 4; gxn = 4; }
    const float gb = (l == 0) ? Bh0[2048 + n] : Bhr[(l - 1) * 3072 + 2048 + n];
    float g0 = gb, g1 = gb, g2 = gb, g3 = gb;
    for (int j = 0; j < gxn; ++j) {
      const float4 p = *(const float4*)&g_partA[(size_t)(gxbase + j) * 8192 + cl * 64 + b0];
      g0 += p.x; g1 += p.y; g2 += p.z; g3 += p.w;
    }
    const int tile64 = n >> 6, cl64 = n & 63;
    const int ghbase = l * 128 + tile64 * 8;
    for (int j = 0; j < 8; ++j) {
      const float4 p = *(const float4*)&g_partB[(size_t)(ghbase + j) * 4096 + cl64 * 64 + b0];
      g0 += p.x; g1 += p.y; g2 += p.z; g3 += p.w;
    }
    g0 = tanhf(g0); g1 = tanhf(g1); g2 = tanhf(g2); g3 = tanhf(g3);
    const int off = l * 65536 + n * 64 + b0;
    const float4 h = *(const float4*)&g_hbuf[par * 196608 + off];
    float4 hn;
    hn.x = z0 * h.x + (1.f - z0) * g0;
    hn.y = z1 * h.y + (1.f - z1) * g1;
    hn.z = z2 * h.z + (1.f - z2) * g2;
    hn.w = z3 * h.w + (1.f - z3) * g3;
    *(float4*)&g_hbuf[(1 - par) * 196608 + off] = hn;
    if (t_l == kS - 1) {
      Out[kBSO + ((size_t)(b0 + 0) * 3 + l) * 1024 + n] = hn.x;
      Out[kBSO + ((size_t)(b0 + 1) * 3 + l) * 1024 + n] = hn.y;
      Out[kBSO + ((size_t)(b0 + 2) * 3 + l) * 1024 + n] = hn.z;
      Out[kBSO + ((size_t)(b0 + 3) * 3 + l) * 1024 + n] = hn.w;
    }
  } else {  // y (A tile is 128 wide: cl = o)
    const int o = c - 3072, ty = tau - 3;
    if (ty < 0 || ty >= kS) return;
    const float bias = Bout[o];
    float s0 = bias, s1 = bias, s2 = bias, s3 = bias;
    for (int j = 0; j < 4; ++j) {
      const float4 p = *(const float4*)&g_partA[(size_t)(408 + j) * 8192 + o * 64 + b0];
      s0 += p.x; s1 += p.y; s2 += p.z; s3 += p.w;
    }
    Out[((size_t)(b0 + 0) * kS + ty) * kO + o] = s0;
    Out[((size_t)(b0 + 1) * kS + ty) * kO + o] = s1;
    Out[((size_t)(b0 + 2) * kS + ty) * kO + o] = s2;
    Out[((size_t)(b0 + 3) * kS + ty) * kO + o] = s3;
  }
}

// ---------------- host ----------------
extern "C" void kernel_launch(void* const* d_in, const int* in_sizes, int n_in,
                              void* d_out, int out_size, void* d_ws, size_t ws_size,
                              hipStream_t stream) {
  const float* X    = (const float*)d_in[0];
  const float* Wx0  = (const float*)d_in[1];
  const float* Wh0  = (const float*)d_in[2];
  const float* bh0  = (const float*)d_in[3];
  const float* Wxr  = (const float*)d_in[4];
  const float* Whr  = (const float*)d_in[5];
  const float* bhr  = (const float*)d_in[6];
  const float* Wout = (const float*)d_in[7];
  const float* bout = (const float*)d_in[8];
  (void)d_ws; (void)ws_size;

  if (n_in != 9 ||
      in_sizes[0] != 64 * 512 * 128 || in_sizes[1] != 3 * 1024 * 128 ||
      in_sizes[2] != 3 * 1024 * 1024 || in_sizes[3] != 3 * 1024 ||
      in_sizes[4] != 2 * 3 * 1024 * 1024 || in_sizes[5] != 2 * 3 * 1024 * 1024 ||
      in_sizes[6] != 2 * 3 * 1024 || in_sizes[7] != 128 * 1024 ||
      in_sizes[8] != 128 || out_size != 64 * 512 * 128 + 64 * 3 * 1024)
    return;  // diagnostic: out stays 0

  float* out = (float*)d_out;

  hipLaunchKernelGGL(zero_hbuf, dim3(1536), dim3(256), 0, stream);
  hipLaunchKernelGGL(transpose_k, dim3(4, 32, 3),   dim3(256), 0, stream, Wx0,  0, 1024, 128);
  hipLaunchKernelGGL(transpose_k, dim3(32, 32, 3),  dim3(256), 0, stream, Wh0,  1, 1024, 1024);
  hipLaunchKernelGGL(transpose_k, dim3(32, 32, 6),  dim3(256), 0, stream, Wxr,  2, 1024, 1024);
  hipLaunchKernelGGL(transpose_k, dim3(32, 32, 6),  dim3(256), 0, stream, Whr,  3, 1024, 1024);
  hipLaunchKernelGGL(transpose_k, dim3(32, 4, 1),   dim3(256), 0, stream, Wout, 4, 128, 1024);
  hipLaunchKernelGGL(transpose_k, dim3(2048, 2, 1), dim3(256), 0, stream, X,    5, 64, 65536);

  for (int tau = 0; tau < kTicks; ++tau) {
    hipLaunchKernelGGL(gemmA, dim3(kTasksA), dim3(256), 0, stream, tau);
    hipLaunchKernelGGL(reduceA, dim3(192), dim3(256), 0, stream, tau, bh0, bhr);
    if (tau < kTicks - 1)
      hipLaunchKernelGGL(gemmB, dim3(kTasksB), dim3(256), 0, stream, tau);
    hipLaunchKernelGGL(reduceB, dim3(200), dim3(256), 0, stream,
                       tau, bh0, bhr, bout, out);
  }
}